// Round 10
// baseline (164.511 us; speedup 1.0000x reference)
//
#include <hip/hip_runtime.h>

#define N_ATOM 10000
#define N_EDGE 40000
#define DD 64
#define BOND_DIM 10
#define EPS_BN 1e-6f
#define EPS_SM 1e-8f
#define GA 8     // atoms per GRU block

typedef __attribute__((ext_vector_type(8))) short short8;
typedef __attribute__((ext_vector_type(4))) float float4v;
typedef __attribute__((ext_vector_type(16))) float float16v;
typedef unsigned int u32;

// ---- workspace layout (dword indices) ----
constexpr size_t OFF_AFRAG   = 0;        // 32768 dw: [d][chunk][lane] x4dw  W'^T A-frags (32x32x16)
constexpr size_t OFF_ATTFRAG = 32768;    // 2048 dw: 8 (fc*2+kh) x 64 lanes x 4 dw (16x16x32 B-frags)
constexpr size_t OFF_ATTB    = 34816;    // 64
constexpr size_t OFF_WIHT    = 34880;    // 12288 WihT[d*192+t]
constexpr size_t OFF_WHHT    = 47168;    // 12288
constexpr size_t OFF_DENOM   = 59456;    // N_ATOM
constexpr size_t OFF_CTX     = 69456;    // N_ATOM*DD
// total 709,456 dwords ~= 2.84 MB

__device__ __forceinline__ unsigned short f2bf(float x) {
    u32 u = __float_as_uint(x);
    u32 r = u + 0x7FFFu + ((u >> 16) & 1u);   // RNE
    return (unsigned short)(r >> 16);
}

// ---------- kernel 0: fold BN, build MFMA fragments, transposes, zero accumulators ----------
__global__ void fold_kernel(const float* enc_W, const float* enc_b,
                            const float* g1, const float* b1,
                            const float* m1, const float* v1,
                            const float* att_W, const float* att_b,
                            const float* g2, const float* b2v,
                            const float* m2, const float* v2,
                            const float* Wih, const float* Whh,
                            float* ws) {
    u32* wsu = (u32*)ws;
    size_t i = (size_t)blockIdx.x * 256 + threadIdx.x;
    if (i < 8192) {
        // W'^T A-fragment for 32x32x16: entry (d, chunk, lane l):
        // m = l&31 -> enc col c = d*64 + chunk*32 + m ; k = 8*(l>>5)+j
        // k<10: enc_W[c][k]*s ; k==10: folded bias ; else 0
        int d = i >> 7, rem = i & 127;
        int ch = rem >> 6, l = rem & 63;
        int c = d * 64 + ch * 32 + (l & 31);
        int kb = 8 * (l >> 5);
        float s = g1[c] * rsqrtf(v1[c] + EPS_BN);
        float bias = enc_b[c] * s + b1[c] - m1[c] * s;
        unsigned short h[8];
#pragma unroll
        for (int j = 0; j < 8; j++) {
            int k = kb + j;
            float v = (k < BOND_DIM) ? enc_W[c * BOND_DIM + k] * s
                                     : ((k == BOND_DIM) ? bias : 0.f);
            h[j] = f2bf(v);
        }
#pragma unroll
        for (int m = 0; m < 4; m++)
            wsu[OFF_AFRAG + i * 4 + m] = (u32)h[2 * m] | ((u32)h[2 * m + 1] << 16);
    } else if (i < 8704) {
        // attention B-fragment (16x16x32), same as verified round-8 code
        int idx = i - 8192;
        int l = idx & 63, fckh = idx >> 6;
        int fc = fckh >> 1, kh = fckh & 1, q = l >> 4;
        int n = (fc << 4) + (l & 15);
        float s = g2[n] * rsqrtf(v2[n] + EPS_BN);
        unsigned short h[8];
#pragma unroll
        for (int j = 0; j < 8; j++) {
            int k = 32 * kh + 8 * q + j;
            h[j] = f2bf(att_W[n * DD + k] * s);
        }
#pragma unroll
        for (int m = 0; m < 4; m++)
            wsu[OFF_ATTFRAG + (size_t)idx * 4 + m] = (u32)h[2 * m] | ((u32)h[2 * m + 1] << 16);
    } else if (i < 8768) {
        int f = i - 8704;
        float s = g2[f] * rsqrtf(v2[f] + EPS_BN);
        ws[OFF_ATTB + f] = att_b[f] * s + b2v[f] - m2[f] * s;
    } else if (i < 21056) {
        int j = i - 8768;
        int d = j / 192, t = j % 192;
        ws[OFF_WIHT + j] = Wih[t * DD + d];
    } else if (i < 33344) {
        int j = i - 21056;
        int d = j / 192, t = j % 192;
        ws[OFF_WHHT + j] = Whh[t * DD + d];
    } else {
        size_t z = i - 33344;
        if (z < (size_t)N_ATOM + (size_t)N_ATOM * DD) ws[OFF_DENOM + z] = 0.f;
    }
}

// ---------- kernel 1: transposed-MFMA edge pipeline ----------
// 128 threads = 2 waves; 32 edges/block (1250 blocks); wave h = d-half.
// GEMM1 (32x32x16): Enc^T chunk = W'^T(A, streamed) @ bond^T(B, stationary)
//   C: col = lane&31 = edge, row = f within chunk -> av = anbr[edge][d] broadcast.
// Partials summed in LDS; each wave then does GEMM2+score+atomics for its 16-edge subtile.
__global__ __launch_bounds__(128) void edge_kernel(
    const float* atom, const int* bidx, const float* bond,
    const float* alignW, const float* alignb,
    const float* ws, float* denom, float* ctx) {
    __shared__ float s_bond[32][BOND_DIM];
    __shared__ float s_anbr[32][65];
    __shared__ float s_nbp[2][32][65];
    __shared__ float s_ex[32];
    __shared__ int   s_tgt[32];

    const int t = threadIdx.x;
    const int lane = t & 63;
    const int h = t >> 6;        // wave = d-half
    const int e0 = blockIdx.x * 32;

    // ---- staging ----
    for (int idx = t; idx < 32 * BOND_DIM; idx += 128)
        s_bond[idx / BOND_DIM][idx % BOND_DIM] = bond[(size_t)e0 * BOND_DIM + idx];
    if (t < 32) s_tgt[t] = bidx[2 * (e0 + t)];
    for (int e = h; e < 32; e += 2) {
        int nbr = bidx[2 * (e0 + e) + 1];
        s_anbr[e][lane] = atom[(size_t)nbr * DD + lane];
    }
    __syncthreads();

    // stationary bond B-fragment: B[k=8*(lane>>5)+j][n=lane&31]
    const int eb = lane & 31;
    const int kb = 8 * (lane >> 5);
    short8 bfrag;
#pragma unroll
    for (int j = 0; j < 8; j++) {
        int k = kb + j;
        unsigned short hh = 0;
        if (k < BOND_DIM) hh = f2bf(s_bond[eb][k]);
        else if (k == BOND_DIM) hh = 0x3F80u;   // 1.0 (bias slot)
        bfrag[j] = (short)hh;
    }

    const short8* afrag = (const short8*)((const u32*)ws + OFF_AFRAG);
    float16v zero16 = {};
    float nb0[16] = {}, nb1[16] = {};
    const int d0 = 32 * h;

    // software-pipelined d-loop (depth 1): 2 A-loads, 1 LDS broadcast, 2 MFMA, 64 fma/fmax
    short8 a0 = afrag[(size_t)(d0 * 2 + 0) * 64 + lane];
    short8 a1 = afrag[(size_t)(d0 * 2 + 1) * 64 + lane];
#pragma unroll 2
    for (int it = 0; it < 32; it++) {
        int d = d0 + it;
        short8 n0, n1;
        if (it < 31) {
            n0 = afrag[(size_t)((d + 1) * 2 + 0) * 64 + lane];
            n1 = afrag[(size_t)((d + 1) * 2 + 1) * 64 + lane];
        }
        float av = s_anbr[eb][d];
        float16v enc0 = __builtin_amdgcn_mfma_f32_32x32x16_bf16(a0, bfrag, zero16, 0, 0, 0);
        float16v enc1 = __builtin_amdgcn_mfma_f32_32x32x16_bf16(a1, bfrag, zero16, 0, 0, 0);
#pragma unroll
        for (int r = 0; r < 16; r++) {
            nb0[r] = fmaf(av, fmaxf(enc0[r], 0.f), nb0[r]);
            nb1[r] = fmaf(av, fmaxf(enc1[r], 0.f), nb1[r]);
        }
        a0 = n0; a1 = n1;
    }

    // write partial nb: f = chunk*32 + (r&3)+8*(r>>2)+4*(lane>>5), edge = lane&31
    const int fro = 4 * (lane >> 5);
#pragma unroll
    for (int r = 0; r < 16; r++) {
        int f = (r & 3) + 8 * (r >> 2) + fro;
        s_nbp[h][eb][f] = nb0[r];
        s_nbp[h][eb][32 + f] = nb1[r];
    }
    __syncthreads();

    // ---- subtile phase: wave h handles edges es..es+15 ----
    const int es = h * 16;
    const int q = lane >> 4;
    const int r16 = lane & 15;

    // GEMM2: atend = nb @ attWT (16x16x32, round-8-verified layouts)
    short8 na[2];
#pragma unroll
    for (int kh = 0; kh < 2; kh++)
#pragma unroll
        for (int j = 0; j < 8; j++) {
            int k = 32 * kh + 8 * q + j;
            na[kh][j] = (short)f2bf(s_nbp[0][es + r16][k] + s_nbp[1][es + r16][k]);
        }
    const short8* battfrag = (const short8*)((const u32*)ws + OFF_ATTFRAG);
    const float4v zero4 = {0.f, 0.f, 0.f, 0.f};
    float4v att[4];
#pragma unroll
    for (int fc = 0; fc < 4; fc++) {
        att[fc] = __builtin_amdgcn_mfma_f32_16x16x32_bf16(na[0], battfrag[(fc * 2 + 0) * 64 + lane], zero4, 0, 0, 0);
        att[fc] = __builtin_amdgcn_mfma_f32_16x16x32_bf16(na[1], battfrag[(fc * 2 + 1) * 64 + lane], att[fc], 0, 0, 0);
        float ab = ws[OFF_ATTB + fc * 16 + r16];
#pragma unroll
        for (int r = 0; r < 4; r++) att[fc][r] += ab;
    }

    // score + exp + denom atomics
    const float aw1 = alignW[lane];
    const float aw2 = alignW[64 + lane];
    const float alb = alignb[0];
#pragma unroll 4
    for (int e = 0; e < 16; e++) {
        int le = es + e;
        int tgt = s_tgt[le];
        float nbv = s_nbp[0][le][lane] + s_nbp[1][le][lane];
        float v = atom[(size_t)tgt * DD + lane] * aw1 + nbv * aw2;
#pragma unroll
        for (int off = 32; off > 0; off >>= 1) v += __shfl_xor(v, off);
        float sc = v + alb;
        sc = sc > 0.f ? sc : 0.01f * sc;   // leaky_relu slope 0.01
        float ex = expf(sc);               // no max-shift: ratio identity, scores O(1)
        if (lane == 0) {
            s_ex[le] = ex;
            atomicAdd(&denom[tgt], ex);
        }
    }

    // ctx segment-sum atomics (C-layout: e = es+4q+r, f = fc*16+r16)
#pragma unroll
    for (int r = 0; r < 4; r++) {
        int le = es + 4 * q + r;
        float exr = s_ex[le];
        int tg = s_tgt[le];
#pragma unroll
        for (int fc = 0; fc < 4; fc++)
            atomicAdd(&ctx[(size_t)tg * DD + fc * 16 + r16], exr * att[fc][r]);
    }
}

// ---------- kernel 2: context finalize (elu) + GRU cell, transposed weights ----------
__global__ __launch_bounds__(192) void gru_kernel(
    const float* atom, const float* ws, const float* denom, const float* ctx,
    const float* bih, const float* bhh, float* out) {
    __shared__ float sctx[GA][DD];
    __shared__ float satom[GA][DD];
    __shared__ float sgi[GA][192];
    __shared__ float sgh[GA][192];
    const int a0 = blockIdx.x * GA;
    const int t = threadIdx.x;

    for (int idx = t; idx < GA * DD; idx += 192) {
        int a = idx >> 6, f = idx & 63;
        float c = ctx[(size_t)(a0 + a) * DD + f] / (denom[a0 + a] + EPS_SM);
        sctx[a][f] = c > 0.f ? c : expm1f(c);  // elu
        satom[a][f] = atom[(size_t)(a0 + a) * DD + f];
    }
    __syncthreads();

    const float* wiht = ws + OFF_WIHT;
    const float* whht = ws + OFF_WHHT;
    float gi[GA], gh[GA];
    const float bi = bih[t], bh = bhh[t];
#pragma unroll
    for (int a = 0; a < GA; a++) { gi[a] = bi; gh[a] = bh; }
#pragma unroll 4
    for (int d = 0; d < DD; d++) {
        float wi = wiht[d * 192 + t];
        float wh = whht[d * 192 + t];
#pragma unroll
        for (int a = 0; a < GA; a++) {
            gi[a] = fmaf(wi, sctx[a][d], gi[a]);
            gh[a] = fmaf(wh, satom[a][d], gh[a]);
        }
    }
#pragma unroll
    for (int a = 0; a < GA; a++) { sgi[a][t] = gi[a]; sgh[a][t] = gh[a]; }
    __syncthreads();

    for (int idx = t; idx < GA * DD; idx += 192) {
        int a = idx >> 6, f = idx & 63;
        float r = 1.f / (1.f + expf(-(sgi[a][f] + sgh[a][f])));
        float z = 1.f / (1.f + expf(-(sgi[a][64 + f] + sgh[a][64 + f])));
        float n = tanhf(sgi[a][128 + f] + r * sgh[a][128 + f]);
        out[(size_t)(a0 + a) * DD + f] = (1.f - z) * n + z * satom[a][f];
    }
}

extern "C" void kernel_launch(void* const* d_in, const int* in_sizes, int n_in,
                              void* d_out, int out_size, void* d_ws, size_t ws_size,
                              hipStream_t stream) {
    const float* atom   = (const float*)d_in[0];
    const int*   bidx   = (const int*)d_in[1];
    const float* bond   = (const float*)d_in[2];
    const float* enc_W  = (const float*)d_in[3];
    const float* enc_b  = (const float*)d_in[4];
    const float* bn1_g  = (const float*)d_in[5];
    const float* bn1_b  = (const float*)d_in[6];
    const float* bn1_m  = (const float*)d_in[7];
    const float* bn1_v  = (const float*)d_in[8];
    const float* alignW = (const float*)d_in[9];
    const float* alignb = (const float*)d_in[10];
    const float* att_W  = (const float*)d_in[11];
    const float* att_b  = (const float*)d_in[12];
    const float* bn2_g  = (const float*)d_in[13];
    const float* bn2_b  = (const float*)d_in[14];
    const float* bn2_m  = (const float*)d_in[15];
    const float* bn2_v  = (const float*)d_in[16];
    const float* gWih   = (const float*)d_in[17];
    const float* gWhh   = (const float*)d_in[18];
    const float* gbih   = (const float*)d_in[19];
    const float* gbhh   = (const float*)d_in[20];

    float* ws  = (float*)d_ws;
    float* out = (float*)d_out;

    fold_kernel<<<2670, 256, 0, stream>>>(enc_W, enc_b, bn1_g, bn1_b, bn1_m, bn1_v,
                                          att_W, att_b, bn2_g, bn2_b, bn2_m, bn2_v,
                                          gWih, gWhh, ws);

    edge_kernel<<<N_EDGE / 32, 128, 0, stream>>>(
        atom, bidx, bond, alignW, alignb, ws,
        ws + OFF_DENOM, ws + OFF_CTX);

    gru_kernel<<<N_ATOM / GA, 192, 0, stream>>>(atom, ws, ws + OFF_DENOM, ws + OFF_CTX,
                                                gbih, gbhh, out);
}

// Round 11
// 148.982 us; speedup vs baseline: 1.1042x; 1.1042x over previous
//
#include <hip/hip_runtime.h>

#define N_ATOM 10000
#define N_EDGE 40000
#define DD 64
#define BOND_DIM 10
#define EPS_BN 1e-6f
#define EPS_SM 1e-8f
#define GA 8     // atoms per GRU block

typedef __attribute__((ext_vector_type(8))) short short8;
typedef __attribute__((ext_vector_type(4))) float float4v;
typedef __attribute__((ext_vector_type(16))) float float16v;
typedef unsigned int u32;

// ---- workspace layout (dword indices) ----
constexpr size_t OFF_AFRAG   = 0;        // 32768 dw: [d][chunk][lane] x4dw  W'^T A-frags (32x32x16)
constexpr size_t OFF_ATTFRAG = 32768;    // 2048 dw: 8 (fc*2+kh) x 64 lanes x 4 dw (16x16x32 B-frags)
constexpr size_t OFF_ATTB    = 34816;    // 64
constexpr size_t OFF_WIHT    = 34880;    // 12288 WihT[d*192+t]
constexpr size_t OFF_WHHT    = 47168;    // 12288
constexpr size_t OFF_DENOM   = 59456;    // N_ATOM
constexpr size_t OFF_CTX     = 69456;    // N_ATOM*DD
// total 709,456 dwords ~= 2.84 MB

__device__ __forceinline__ unsigned short f2bf(float x) {
    u32 u = __float_as_uint(x);
    u32 r = u + 0x7FFFu + ((u >> 16) & 1u);   // RNE
    return (unsigned short)(r >> 16);
}

// ---------- kernel 0: fold BN, build MFMA fragments, transposes, zero accumulators ----------
__global__ void fold_kernel(const float* enc_W, const float* enc_b,
                            const float* g1, const float* b1,
                            const float* m1, const float* v1,
                            const float* att_W, const float* att_b,
                            const float* g2, const float* b2v,
                            const float* m2, const float* v2,
                            const float* Wih, const float* Whh,
                            float* ws) {
    u32* wsu = (u32*)ws;
    size_t i = (size_t)blockIdx.x * 256 + threadIdx.x;
    if (i < 8192) {
        // W'^T A-fragment for 32x32x16: m = l&31 -> enc col c = d*64 + ch*32 + m ; k = 8*(l>>5)+j
        int d = i >> 7, rem = i & 127;
        int ch = rem >> 6, l = rem & 63;
        int c = d * 64 + ch * 32 + (l & 31);
        int kb = 8 * (l >> 5);
        float s = g1[c] * rsqrtf(v1[c] + EPS_BN);
        float bias = enc_b[c] * s + b1[c] - m1[c] * s;
        unsigned short h[8];
#pragma unroll
        for (int j = 0; j < 8; j++) {
            int k = kb + j;
            float v = (k < BOND_DIM) ? enc_W[c * BOND_DIM + k] * s
                                     : ((k == BOND_DIM) ? bias : 0.f);
            h[j] = f2bf(v);
        }
#pragma unroll
        for (int m = 0; m < 4; m++)
            wsu[OFF_AFRAG + i * 4 + m] = (u32)h[2 * m] | ((u32)h[2 * m + 1] << 16);
    } else if (i < 8704) {
        // attention B-fragment (16x16x32), round-8-verified layout
        int idx = i - 8192;
        int l = idx & 63, fckh = idx >> 6;
        int fc = fckh >> 1, kh = fckh & 1, q = l >> 4;
        int n = (fc << 4) + (l & 15);
        float s = g2[n] * rsqrtf(v2[n] + EPS_BN);
        unsigned short h[8];
#pragma unroll
        for (int j = 0; j < 8; j++) {
            int k = 32 * kh + 8 * q + j;
            h[j] = f2bf(att_W[n * DD + k] * s);
        }
#pragma unroll
        for (int m = 0; m < 4; m++)
            wsu[OFF_ATTFRAG + (size_t)idx * 4 + m] = (u32)h[2 * m] | ((u32)h[2 * m + 1] << 16);
    } else if (i < 8768) {
        int f = i - 8704;
        float s = g2[f] * rsqrtf(v2[f] + EPS_BN);
        ws[OFF_ATTB + f] = att_b[f] * s + b2v[f] - m2[f] * s;
    } else if (i < 21056) {
        int j = i - 8768;
        int d = j / 192, t = j % 192;
        ws[OFF_WIHT + j] = Wih[t * DD + d];
    } else if (i < 33344) {
        int j = i - 21056;
        int d = j / 192, t = j % 192;
        ws[OFF_WHHT + j] = Whh[t * DD + d];
    } else {
        size_t z = i - 33344;
        if (z < (size_t)N_ATOM + (size_t)N_ATOM * DD) ws[OFF_DENOM + z] = 0.f;
    }
}

// ---------- kernel 1: transposed-MFMA edge pipeline, 4-way d-split ----------
// 256 threads = 4 waves; 32 edges/block (1250 blocks); wave h owns d-quarter 16h..16h+15.
// In-place LDS partial reduction keeps 2 buffers (26.5 KB -> 6 blocks/CU).
// Phase B: waves 0/1 = GEMM2 subtiles, waves 2/3 = score subtiles, then ctx atomics.
__global__ __launch_bounds__(256, 5) void edge_kernel(
    const float* atom, const int* bidx, const float* bond,
    const float* alignW, const float* alignb,
    const float* ws, float* denom, float* ctx) {
    __shared__ float s_bond[32][BOND_DIM];
    __shared__ float s_anbr[32][65];
    __shared__ float s_nbp[2][32][65];
    __shared__ float s_ex[32];
    __shared__ int   s_tgt[32];

    const int t = threadIdx.x;
    const int lane = t & 63;
    const int h = t >> 6;        // wave = d-quarter
    const int e0 = blockIdx.x * 32;

    // ---- staging ----
    for (int idx = t; idx < 32 * BOND_DIM; idx += 256)
        s_bond[idx / BOND_DIM][idx % BOND_DIM] = bond[(size_t)e0 * BOND_DIM + idx];
    if (t < 32) s_tgt[t] = bidx[2 * (e0 + t)];
    for (int e = h; e < 32; e += 4) {
        int nbr = bidx[2 * (e0 + e) + 1];
        s_anbr[e][lane] = atom[(size_t)nbr * DD + lane];
    }
    __syncthreads();

    // stationary bond B-fragment: B[k=8*(lane>>5)+j][n=lane&31]
    const int eb = lane & 31;
    const int kb = 8 * (lane >> 5);
    short8 bfrag;
#pragma unroll
    for (int j = 0; j < 8; j++) {
        int k = kb + j;
        unsigned short hh = 0;
        if (k < BOND_DIM) hh = f2bf(s_bond[eb][k]);
        else if (k == BOND_DIM) hh = 0x3F80u;   // 1.0 (bias slot)
        bfrag[j] = (short)hh;
    }

    const short8* afrag = (const short8*)((const u32*)ws + OFF_AFRAG);
    float16v zero16 = {};
    float nb0[16] = {}, nb1[16] = {};
    const int d0 = 16 * h;
    const int ph = blockIdx.x & 15;   // de-correlate chip-wide W' sweep

    // software-pipelined 16-iter d-loop with per-block phase rotation
    int dcur = d0 + (ph & 15);
    short8 a0 = afrag[(size_t)(dcur * 2 + 0) * 64 + lane];
    short8 a1 = afrag[(size_t)(dcur * 2 + 1) * 64 + lane];
#pragma unroll 2
    for (int it = 0; it < 16; it++) {
        int dnxt = d0 + ((it + 1 + ph) & 15);
        short8 n0, n1;
        if (it < 15) {
            n0 = afrag[(size_t)(dnxt * 2 + 0) * 64 + lane];
            n1 = afrag[(size_t)(dnxt * 2 + 1) * 64 + lane];
        }
        float av = s_anbr[eb][dcur];
        float16v enc0 = __builtin_amdgcn_mfma_f32_32x32x16_bf16(a0, bfrag, zero16, 0, 0, 0);
        float16v enc1 = __builtin_amdgcn_mfma_f32_32x32x16_bf16(a1, bfrag, zero16, 0, 0, 0);
#pragma unroll
        for (int r = 0; r < 16; r++) {
            nb0[r] = fmaf(av, fmaxf(enc0[r], 0.f), nb0[r]);
            nb1[r] = fmaf(av, fmaxf(enc1[r], 0.f), nb1[r]);
        }
        a0 = n0; a1 = n1; dcur = dnxt;
    }

    // partial nb reduction: waves 0,1 write buffers; waves 2,3 add in place.
    // f = chunk*32 + (r&3)+8*(r>>2)+4*(lane>>5), edge = lane&31 (m74/m101 layout)
    const int fro = 4 * (lane >> 5);
    if (h < 2) {
#pragma unroll
        for (int r = 0; r < 16; r++) {
            int f = (r & 3) + 8 * (r >> 2) + fro;
            s_nbp[h][eb][f] = nb0[r];
            s_nbp[h][eb][32 + f] = nb1[r];
        }
    }
    __syncthreads();
    if (h >= 2) {
#pragma unroll
        for (int r = 0; r < 16; r++) {
            int f = (r & 3) + 8 * (r >> 2) + fro;
            s_nbp[h - 2][eb][f] += nb0[r];
            s_nbp[h - 2][eb][32 + f] += nb1[r];
        }
    }
    __syncthreads();

    // ---- phase B: split across 4 waves; subtile es = (h&1)*16 ----
    const int es = (h & 1) * 16;
    const int q = lane >> 4;
    const int r16 = lane & 15;
    float4v att[4];

    if (h < 2) {
        // GEMM2: atend = nb @ attWT (16x16x32, round-8-verified layouts)
        short8 na[2];
#pragma unroll
        for (int kh = 0; kh < 2; kh++)
#pragma unroll
            for (int j = 0; j < 8; j++) {
                int k = 32 * kh + 8 * q + j;
                na[kh][j] = (short)f2bf(s_nbp[0][es + r16][k] + s_nbp[1][es + r16][k]);
            }
        const short8* battfrag = (const short8*)((const u32*)ws + OFF_ATTFRAG);
        const float4v zero4 = {0.f, 0.f, 0.f, 0.f};
#pragma unroll
        for (int fc = 0; fc < 4; fc++) {
            att[fc] = __builtin_amdgcn_mfma_f32_16x16x32_bf16(na[0], battfrag[(fc * 2 + 0) * 64 + lane], zero4, 0, 0, 0);
            att[fc] = __builtin_amdgcn_mfma_f32_16x16x32_bf16(na[1], battfrag[(fc * 2 + 1) * 64 + lane], att[fc], 0, 0, 0);
            float ab = ws[OFF_ATTB + fc * 16 + r16];
#pragma unroll
            for (int r = 0; r < 4; r++) att[fc][r] += ab;
        }
    } else {
        // score + exp + denom atomics for this subtile's 16 edges
        const float aw1 = alignW[lane];
        const float aw2 = alignW[64 + lane];
        const float alb = alignb[0];
#pragma unroll 4
        for (int e = 0; e < 16; e++) {
            int le = es + e;
            int tgt = s_tgt[le];
            float nbv = s_nbp[0][le][lane] + s_nbp[1][le][lane];
            float v = atom[(size_t)tgt * DD + lane] * aw1 + nbv * aw2;
#pragma unroll
            for (int off = 32; off > 0; off >>= 1) v += __shfl_xor(v, off);
            float sc = v + alb;
            sc = sc > 0.f ? sc : 0.01f * sc;   // leaky_relu slope 0.01
            float ex = expf(sc);               // no max-shift: ratio identity, scores O(1)
            if (lane == 0) {
                s_ex[le] = ex;
                atomicAdd(&denom[tgt], ex);
            }
        }
    }
    __syncthreads();

    if (h < 2) {
        // ctx segment-sum atomics (C-layout: e = es+4q+r, f = fc*16+r16)
#pragma unroll
        for (int r = 0; r < 4; r++) {
            int le = es + 4 * q + r;
            float exr = s_ex[le];
            int tg = s_tgt[le];
#pragma unroll
            for (int fc = 0; fc < 4; fc++)
                atomicAdd(&ctx[(size_t)tg * DD + fc * 16 + r16], exr * att[fc][r]);
        }
    }
}

// ---------- kernel 2: context finalize (elu) + GRU cell, transposed weights ----------
__global__ __launch_bounds__(192) void gru_kernel(
    const float* atom, const float* ws, const float* denom, const float* ctx,
    const float* bih, const float* bhh, float* out) {
    __shared__ float sctx[GA][DD];
    __shared__ float satom[GA][DD];
    __shared__ float sgi[GA][192];
    __shared__ float sgh[GA][192];
    const int a0 = blockIdx.x * GA;
    const int t = threadIdx.x;

    for (int idx = t; idx < GA * DD; idx += 192) {
        int a = idx >> 6, f = idx & 63;
        float c = ctx[(size_t)(a0 + a) * DD + f] / (denom[a0 + a] + EPS_SM);
        sctx[a][f] = c > 0.f ? c : expm1f(c);  // elu
        satom[a][f] = atom[(size_t)(a0 + a) * DD + f];
    }
    __syncthreads();

    const float* wiht = ws + OFF_WIHT;
    const float* whht = ws + OFF_WHHT;
    float gi[GA], gh[GA];
    const float bi = bih[t], bh = bhh[t];
#pragma unroll
    for (int a = 0; a < GA; a++) { gi[a] = bi; gh[a] = bh; }
#pragma unroll 4
    for (int d = 0; d < DD; d++) {
        float wi = wiht[d * 192 + t];
        float wh = whht[d * 192 + t];
#pragma unroll
        for (int a = 0; a < GA; a++) {
            gi[a] = fmaf(wi, sctx[a][d], gi[a]);
            gh[a] = fmaf(wh, satom[a][d], gh[a]);
        }
    }
#pragma unroll
    for (int a = 0; a < GA; a++) { sgi[a][t] = gi[a]; sgh[a][t] = gh[a]; }
    __syncthreads();

    for (int idx = t; idx < GA * DD; idx += 192) {
        int a = idx >> 6, f = idx & 63;
        float r = 1.f / (1.f + expf(-(sgi[a][f] + sgh[a][f])));
        float z = 1.f / (1.f + expf(-(sgi[a][64 + f] + sgh[a][64 + f])));
        float n = tanhf(sgi[a][128 + f] + r * sgh[a][128 + f]);
        out[(size_t)(a0 + a) * DD + f] = (1.f - z) * n + z * satom[a][f];
    }
}

extern "C" void kernel_launch(void* const* d_in, const int* in_sizes, int n_in,
                              void* d_out, int out_size, void* d_ws, size_t ws_size,
                              hipStream_t stream) {
    const float* atom   = (const float*)d_in[0];
    const int*   bidx   = (const int*)d_in[1];
    const float* bond   = (const float*)d_in[2];
    const float* enc_W  = (const float*)d_in[3];
    const float* enc_b  = (const float*)d_in[4];
    const float* bn1_g  = (const float*)d_in[5];
    const float* bn1_b  = (const float*)d_in[6];
    const float* bn1_m  = (const float*)d_in[7];
    const float* bn1_v  = (const float*)d_in[8];
    const float* alignW = (const float*)d_in[9];
    const float* alignb = (const float*)d_in[10];
    const float* att_W  = (const float*)d_in[11];
    const float* att_b  = (const float*)d_in[12];
    const float* bn2_g  = (const float*)d_in[13];
    const float* bn2_b  = (const float*)d_in[14];
    const float* bn2_m  = (const float*)d_in[15];
    const float* bn2_v  = (const float*)d_in[16];
    const float* gWih   = (const float*)d_in[17];
    const float* gWhh   = (const float*)d_in[18];
    const float* gbih   = (const float*)d_in[19];
    const float* gbhh   = (const float*)d_in[20];

    float* ws  = (float*)d_ws;
    float* out = (float*)d_out;

    fold_kernel<<<2670, 256, 0, stream>>>(enc_W, enc_b, bn1_g, bn1_b, bn1_m, bn1_v,
                                          att_W, att_b, bn2_g, bn2_b, bn2_m, bn2_v,
                                          gWih, gWhh, ws);

    edge_kernel<<<N_EDGE / 32, 256, 0, stream>>>(
        atom, bidx, bond, alignW, alignb, ws,
        ws + OFF_DENOM, ws + OFF_CTX);

    gru_kernel<<<N_ATOM / GA, 192, 0, stream>>>(atom, ws, ws + OFF_DENOM, ws + OFF_CTX,
                                                gbih, gbhh, out);
}

// Round 12
// 147.469 us; speedup vs baseline: 1.1156x; 1.0103x over previous
//
#include <hip/hip_runtime.h>

#define N_ATOM 10000
#define N_EDGE 40000
#define DD 64
#define BOND_DIM 10
#define EPS_BN 1e-6f
#define EPS_SM 1e-8f
#define GA 8     // atoms per GRU block

typedef __attribute__((ext_vector_type(8))) short short8;
typedef __attribute__((ext_vector_type(2))) float float2v;
typedef __attribute__((ext_vector_type(4))) float float4v;
typedef __attribute__((ext_vector_type(16))) float float16v;
typedef unsigned int u32;

// ---- workspace layout (dword indices) ----
constexpr size_t OFF_AFRAG   = 0;        // 32768 dw: [d][chunk][lane] x4dw  W'^T A-frags (32x32x16)
constexpr size_t OFF_ATTFRAG = 32768;    // 2048 dw: 8 (fc*2+kh) x 64 lanes x 4 dw (16x16x32 B-frags)
constexpr size_t OFF_ATTB    = 34816;    // 64
constexpr size_t OFF_WIHT    = 34880;    // 12288 WihT[d*192+t]
constexpr size_t OFF_WHHT    = 47168;    // 12288
constexpr size_t OFF_DENOM   = 59456;    // N_ATOM
constexpr size_t OFF_CTX     = 69456;    // N_ATOM*DD
// total 709,456 dwords ~= 2.84 MB

__device__ __forceinline__ unsigned short f2bf(float x) {
    u32 u = __float_as_uint(x);
    u32 r = u + 0x7FFFu + ((u >> 16) & 1u);   // RNE
    return (unsigned short)(r >> 16);
}

// ---------- kernel 0: fold BN, build MFMA fragments, transposes, zero accumulators ----------
__global__ void fold_kernel(const float* enc_W, const float* enc_b,
                            const float* g1, const float* b1,
                            const float* m1, const float* v1,
                            const float* att_W, const float* att_b,
                            const float* g2, const float* b2v,
                            const float* m2, const float* v2,
                            const float* Wih, const float* Whh,
                            float* ws) {
    u32* wsu = (u32*)ws;
    size_t i = (size_t)blockIdx.x * 256 + threadIdx.x;
    if (i < 8192) {
        // W'^T A-fragment for 32x32x16: m = l&31 -> enc col c = d*64 + ch*32 + m ; k = 8*(l>>5)+j
        int d = i >> 7, rem = i & 127;
        int ch = rem >> 6, l = rem & 63;
        int c = d * 64 + ch * 32 + (l & 31);
        int kb = 8 * (l >> 5);
        float s = g1[c] * rsqrtf(v1[c] + EPS_BN);
        float bias = enc_b[c] * s + b1[c] - m1[c] * s;
        unsigned short h[8];
#pragma unroll
        for (int j = 0; j < 8; j++) {
            int k = kb + j;
            float v = (k < BOND_DIM) ? enc_W[c * BOND_DIM + k] * s
                                     : ((k == BOND_DIM) ? bias : 0.f);
            h[j] = f2bf(v);
        }
#pragma unroll
        for (int m = 0; m < 4; m++)
            wsu[OFF_AFRAG + i * 4 + m] = (u32)h[2 * m] | ((u32)h[2 * m + 1] << 16);
    } else if (i < 8704) {
        // attention B-fragment (16x16x32), round-8-verified layout
        int idx = i - 8192;
        int l = idx & 63, fckh = idx >> 6;
        int fc = fckh >> 1, kh = fckh & 1, q = l >> 4;
        int n = (fc << 4) + (l & 15);
        float s = g2[n] * rsqrtf(v2[n] + EPS_BN);
        unsigned short h[8];
#pragma unroll
        for (int j = 0; j < 8; j++) {
            int k = 32 * kh + 8 * q + j;
            h[j] = f2bf(att_W[n * DD + k] * s);
        }
#pragma unroll
        for (int m = 0; m < 4; m++)
            wsu[OFF_ATTFRAG + (size_t)idx * 4 + m] = (u32)h[2 * m] | ((u32)h[2 * m + 1] << 16);
    } else if (i < 8768) {
        int f = i - 8704;
        float s = g2[f] * rsqrtf(v2[f] + EPS_BN);
        ws[OFF_ATTB + f] = att_b[f] * s + b2v[f] - m2[f] * s;
    } else if (i < 21056) {
        int j = i - 8768;
        int d = j / 192, t = j % 192;
        ws[OFF_WIHT + j] = Wih[t * DD + d];
    } else if (i < 33344) {
        int j = i - 21056;
        int d = j / 192, t = j % 192;
        ws[OFF_WHHT + j] = Whh[t * DD + d];
    } else {
        size_t z = i - 33344;
        if (z < (size_t)N_ATOM + (size_t)N_ATOM * DD) ws[OFF_DENOM + z] = 0.f;
    }
}

// ---------- kernel 1: transposed-MFMA edge pipeline, 4-way d-split ----------
// 256 threads = 4 waves; 32 edges/block (1250 blocks); wave h owns d-quarter.
// Full-unroll main loop (compiler-scheduled prefetch, no manual rotation);
// einsum accumulated as float2 -> v_pk_fma_f32.
__global__ __launch_bounds__(256, 5) void edge_kernel(
    const float* atom, const int* bidx, const float* bond,
    const float* alignW, const float* alignb,
    const float* ws, float* denom, float* ctx) {
    __shared__ float s_bond[32][BOND_DIM];
    __shared__ float s_anbr[32][65];
    __shared__ float s_nbp[2][32][65];
    __shared__ float s_ex[32];
    __shared__ int   s_tgt[32];

    const int t = threadIdx.x;
    const int lane = t & 63;
    const int h = t >> 6;        // wave = d-quarter
    const int e0 = blockIdx.x * 32;

    // ---- staging ----
    for (int idx = t; idx < 32 * BOND_DIM; idx += 256)
        s_bond[idx / BOND_DIM][idx % BOND_DIM] = bond[(size_t)e0 * BOND_DIM + idx];
    if (t < 32) s_tgt[t] = bidx[2 * (e0 + t)];
    for (int e = h; e < 32; e += 4) {
        int nbr = bidx[2 * (e0 + e) + 1];
        s_anbr[e][lane] = atom[(size_t)nbr * DD + lane];
    }
    __syncthreads();

    // stationary bond B-fragment: B[k=8*(lane>>5)+j][n=lane&31]
    const int eb = lane & 31;
    const int kb = 8 * (lane >> 5);
    short8 bfrag;
#pragma unroll
    for (int j = 0; j < 8; j++) {
        int k = kb + j;
        unsigned short hh = 0;
        if (k < BOND_DIM) hh = f2bf(s_bond[eb][k]);
        else if (k == BOND_DIM) hh = 0x3F80u;   // 1.0 (bias slot)
        bfrag[j] = (short)hh;
    }

    const short8* afrag = (const short8*)((const u32*)ws + OFF_AFRAG);
    const float16v zero16 = {};
    const float2v zero2 = {0.f, 0.f};
    float2v nb0[8] = {}, nb1[8] = {};
    const int d0 = 16 * h;
    const int ph = blockIdx.x & 15;   // de-correlate chip-wide W' sweep

    // full-unroll d-loop: direct indexed loads, compiler schedules vmcnt prefetch
#pragma unroll
    for (int it = 0; it < 16; it++) {
        int d = d0 + ((it + ph) & 15);
        short8 a0 = afrag[(size_t)(d * 2 + 0) * 64 + lane];
        short8 a1 = afrag[(size_t)(d * 2 + 1) * 64 + lane];
        float av = s_anbr[eb][d];
        float2v av2 = {av, av};
        float16v enc0 = __builtin_amdgcn_mfma_f32_32x32x16_bf16(a0, bfrag, zero16, 0, 0, 0);
        float16v enc1 = __builtin_amdgcn_mfma_f32_32x32x16_bf16(a1, bfrag, zero16, 0, 0, 0);
#pragma unroll
        for (int r = 0; r < 8; r++) {
            float2v e0v = {enc0[2 * r], enc0[2 * r + 1]};
            float2v e1v = {enc1[2 * r], enc1[2 * r + 1]};
            e0v = __builtin_elementwise_max(e0v, zero2);
            e1v = __builtin_elementwise_max(e1v, zero2);
            nb0[r] += av2 * e0v;    // contracts to v_pk_fma_f32
            nb1[r] += av2 * e1v;
        }
    }

    // partial nb reduction: waves 0,1 write buffers; waves 2,3 add in place.
    // element e=2r,2r+1 -> f = (e&3)+8*(e>>2)+fro, f(2r+1)=f(2r)+1 (m74/m101 layout)
    const int fro = 4 * (lane >> 5);
    if (h < 2) {
#pragma unroll
        for (int r = 0; r < 8; r++) {
            int e = 2 * r;
            int f = (e & 3) + 8 * (e >> 2) + fro;
            s_nbp[h][eb][f] = nb0[r].x;
            s_nbp[h][eb][f + 1] = nb0[r].y;
            s_nbp[h][eb][32 + f] = nb1[r].x;
            s_nbp[h][eb][32 + f + 1] = nb1[r].y;
        }
    }
    __syncthreads();
    if (h >= 2) {
#pragma unroll
        for (int r = 0; r < 8; r++) {
            int e = 2 * r;
            int f = (e & 3) + 8 * (e >> 2) + fro;
            s_nbp[h - 2][eb][f] += nb0[r].x;
            s_nbp[h - 2][eb][f + 1] += nb0[r].y;
            s_nbp[h - 2][eb][32 + f] += nb1[r].x;
            s_nbp[h - 2][eb][32 + f + 1] += nb1[r].y;
        }
    }
    __syncthreads();

    // ---- phase B: split across 4 waves; subtile es = (h&1)*16 ----
    const int es = (h & 1) * 16;
    const int q = lane >> 4;
    const int r16 = lane & 15;
    float4v att[4];

    if (h < 2) {
        // GEMM2: atend = nb @ attWT (16x16x32, round-8-verified layouts)
        short8 na[2];
#pragma unroll
        for (int kh = 0; kh < 2; kh++)
#pragma unroll
            for (int j = 0; j < 8; j++) {
                int k = 32 * kh + 8 * q + j;
                na[kh][j] = (short)f2bf(s_nbp[0][es + r16][k] + s_nbp[1][es + r16][k]);
            }
        const short8* battfrag = (const short8*)((const u32*)ws + OFF_ATTFRAG);
        const float4v zero4 = {0.f, 0.f, 0.f, 0.f};
#pragma unroll
        for (int fc = 0; fc < 4; fc++) {
            att[fc] = __builtin_amdgcn_mfma_f32_16x16x32_bf16(na[0], battfrag[(fc * 2 + 0) * 64 + lane], zero4, 0, 0, 0);
            att[fc] = __builtin_amdgcn_mfma_f32_16x16x32_bf16(na[1], battfrag[(fc * 2 + 1) * 64 + lane], att[fc], 0, 0, 0);
            float ab = ws[OFF_ATTB + fc * 16 + r16];
#pragma unroll
            for (int r = 0; r < 4; r++) att[fc][r] += ab;
        }
    } else {
        // score + exp + denom atomics for this subtile's 16 edges
        const float aw1 = alignW[lane];
        const float aw2 = alignW[64 + lane];
        const float alb = alignb[0];
#pragma unroll 4
        for (int e = 0; e < 16; e++) {
            int le = es + e;
            int tgt = s_tgt[le];
            float nbv = s_nbp[0][le][lane] + s_nbp[1][le][lane];
            float v = atom[(size_t)tgt * DD + lane] * aw1 + nbv * aw2;
#pragma unroll
            for (int off = 32; off > 0; off >>= 1) v += __shfl_xor(v, off);
            float sc = v + alb;
            sc = sc > 0.f ? sc : 0.01f * sc;   // leaky_relu slope 0.01
            float ex = expf(sc);               // no max-shift: ratio identity, scores O(1)
            if (lane == 0) {
                s_ex[le] = ex;
                atomicAdd(&denom[tgt], ex);
            }
        }
    }
    __syncthreads();

    if (h < 2) {
        // ctx segment-sum atomics (C-layout: e = es+4q+r, f = fc*16+r16)
#pragma unroll
        for (int r = 0; r < 4; r++) {
            int le = es + 4 * q + r;
            float exr = s_ex[le];
            int tg = s_tgt[le];
#pragma unroll
            for (int fc = 0; fc < 4; fc++)
                atomicAdd(&ctx[(size_t)tg * DD + fc * 16 + r16], exr * att[fc][r]);
        }
    }
}

// ---------- kernel 2: context finalize (elu) + GRU cell, transposed weights ----------
__global__ __launch_bounds__(192) void gru_kernel(
    const float* atom, const float* ws, const float* denom, const float* ctx,
    const float* bih, const float* bhh, float* out) {
    __shared__ float sctx[GA][DD];
    __shared__ float satom[GA][DD];
    __shared__ float sgi[GA][192];
    __shared__ float sgh[GA][192];
    const int a0 = blockIdx.x * GA;
    const int t = threadIdx.x;

    for (int idx = t; idx < GA * DD; idx += 192) {
        int a = idx >> 6, f = idx & 63;
        float c = ctx[(size_t)(a0 + a) * DD + f] / (denom[a0 + a] + EPS_SM);
        sctx[a][f] = c > 0.f ? c : expm1f(c);  // elu
        satom[a][f] = atom[(size_t)(a0 + a) * DD + f];
    }
    __syncthreads();

    const float* wiht = ws + OFF_WIHT;
    const float* whht = ws + OFF_WHHT;
    float gi[GA], gh[GA];
    const float bi = bih[t], bh = bhh[t];
#pragma unroll
    for (int a = 0; a < GA; a++) { gi[a] = bi; gh[a] = bh; }
#pragma unroll 4
    for (int d = 0; d < DD; d++) {
        float wi = wiht[d * 192 + t];
        float wh = whht[d * 192 + t];
#pragma unroll
        for (int a = 0; a < GA; a++) {
            gi[a] = fmaf(wi, sctx[a][d], gi[a]);
            gh[a] = fmaf(wh, satom[a][d], gh[a]);
        }
    }
#pragma unroll
    for (int a = 0; a < GA; a++) { sgi[a][t] = gi[a]; sgh[a][t] = gh[a]; }
    __syncthreads();

    for (int idx = t; idx < GA * DD; idx += 192) {
        int a = idx >> 6, f = idx & 63;
        float r = 1.f / (1.f + expf(-(sgi[a][f] + sgh[a][f])));
        float z = 1.f / (1.f + expf(-(sgi[a][64 + f] + sgh[a][64 + f])));
        float n = tanhf(sgi[a][128 + f] + r * sgh[a][128 + f]);
        out[(size_t)(a0 + a) * DD + f] = (1.f - z) * n + z * satom[a][f];
    }
}

extern "C" void kernel_launch(void* const* d_in, const int* in_sizes, int n_in,
                              void* d_out, int out_size, void* d_ws, size_t ws_size,
                              hipStream_t stream) {
    const float* atom   = (const float*)d_in[0];
    const int*   bidx   = (const int*)d_in[1];
    const float* bond   = (const float*)d_in[2];
    const float* enc_W  = (const float*)d_in[3];
    const float* enc_b  = (const float*)d_in[4];
    const float* bn1_g  = (const float*)d_in[5];
    const float* bn1_b  = (const float*)d_in[6];
    const float* bn1_m  = (const float*)d_in[7];
    const float* bn1_v  = (const float*)d_in[8];
    const float* alignW = (const float*)d_in[9];
    const float* alignb = (const float*)d_in[10];
    const float* att_W  = (const float*)d_in[11];
    const float* att_b  = (const float*)d_in[12];
    const float* bn2_g  = (const float*)d_in[13];
    const float* bn2_b  = (const float*)d_in[14];
    const float* bn2_m  = (const float*)d_in[15];
    const float* bn2_v  = (const float*)d_in[16];
    const float* gWih   = (const float*)d_in[17];
    const float* gWhh   = (const float*)d_in[18];
    const float* gbih   = (const float*)d_in[19];
    const float* gbhh   = (const float*)d_in[20];

    float* ws  = (float*)d_ws;
    float* out = (float*)d_out;

    fold_kernel<<<2670, 256, 0, stream>>>(enc_W, enc_b, bn1_g, bn1_b, bn1_m, bn1_v,
                                          att_W, att_b, bn2_g, bn2_b, bn2_m, bn2_v,
                                          gWih, gWhh, ws);

    edge_kernel<<<N_EDGE / 32, 256, 0, stream>>>(
        atom, bidx, bond, alignW, alignb, ws,
        ws + OFF_DENOM, ws + OFF_CTX);

    gru_kernel<<<N_ATOM / GA, 192, 0, stream>>>(atom, ws, ws + OFF_DENOM, ws + OFF_CTX,
                                                gbih, gbhh, out);
}